// Round 18
// baseline (281.884 us; speedup 1.0000x reference)
//
#include <hip/hip_runtime.h>
#include <hip/hip_bf16.h>
#include <cstdint>
#include <cstddef>

// Problem constants (match reference)
constexpr int B_N = 2;
constexpr int C_N = 256;
constexpr int N_N = 4096;
constexpr int NC  = N_N * C_N;        // 1,048,576
constexpr float EPS_  = 1e-5f;
constexpr float INV_T = 1.0f / 16.0f; // 1/sqrt(C)

using bf16x8 = __attribute__((ext_vector_type(8))) __bf16;
using f32x4  = __attribute__((ext_vector_type(4))) float;
using i32x4  = __attribute__((ext_vector_type(4))) int;

typedef __attribute__((address_space(1))) const void g1_void;
typedef __attribute__((address_space(3))) void l3_void;

__device__ __forceinline__ uint16_t f2bf(float f) {
  uint32_t u = __builtin_bit_cast(uint32_t, f);
  u += 0x7fffu + ((u >> 16) & 1u);
  return (uint16_t)(u >> 16);
}
__device__ __forceinline__ float bf2f(uint16_t h) {
  return __builtin_bit_cast(float, (uint32_t)h << 16);
}

// ---------------- weight cast: 4 (C,C) f32 -> bf16 ----------------
__global__ __launch_bounds__(256) void cast_w_kernel(
    const float* __restrict__ w0, const float* __restrict__ w1,
    const float* __restrict__ w2, const float* __restrict__ w3,
    uint16_t* __restrict__ o0, uint16_t* __restrict__ o1,
    uint16_t* __restrict__ o2, uint16_t* __restrict__ o3) {
  int i = blockIdx.x * 256 + threadIdx.x;
  int m = blockIdx.y;
  const float* s = (m == 0) ? w0 : (m == 1) ? w1 : (m == 2) ? w2 : w3;
  uint16_t* d = (m == 0) ? o0 : (m == 1) ? o1 : (m == 2) ? o2 : o3;
  d[i] = f2bf(s[i]);
}

// ---------------- transpose x (B,C,N) -> x_t bf16 (B,N,C) ----------------
__global__ __launch_bounds__(256) void transpose_x_kernel(
    const float* __restrict__ x, uint16_t* __restrict__ xtb) {
  __shared__ float tile[32][33];
  int b = blockIdx.z;
  int c0 = blockIdx.x * 32, n0 = blockIdx.y * 32;
  int tc = threadIdx.x & 31, tr = threadIdx.x >> 5;
  const float* xb = x + (size_t)b * C_N * N_N;
#pragma unroll
  for (int pp = 0; pp < 4; pp++) {
    int r = tr + pp * 8;
    tile[r][tc] = xb[(size_t)(c0 + r) * N_N + n0 + tc];
  }
  __syncthreads();
  uint16_t* xtbp = xtb + (size_t)b * NC;
#pragma unroll
  for (int pp = 0; pp < 4; pp++) {
    int r = tr + pp * 8;
    xtbp[(size_t)(n0 + r) * C_N + c0 + tc] = f2bf(tile[tc][r]);
  }
}

// ---------------- GEMM: Yt[b][n][c_out] = sum_k Wb[c_out][k]*Xb[b][n][k] + bias ----------------
__global__ __launch_bounds__(256) void gemm_kernel(
    const uint16_t* __restrict__ Wb, const uint16_t* __restrict__ Xb,
    const float* __restrict__ bias, float* __restrict__ Yt) {
  int b = blockIdx.z;
  int n0 = blockIdx.x * 64;
  int c0 = blockIdx.y * 64;
  int w = threadIdx.x >> 6;
  int l = threadIdx.x & 63;
  int lr = l & 15, g = l >> 4;
  const uint16_t* xp = Xb + (size_t)b * NC;
  f32x4 acc[4] = {{0.f,0.f,0.f,0.f},{0.f,0.f,0.f,0.f},{0.f,0.f,0.f,0.f},{0.f,0.f,0.f,0.f}};
  const uint16_t* wrow = Wb + (size_t)(c0 + w * 16 + lr) * C_N + g * 8;
#pragma unroll
  for (int kk = 0; kk < 8; kk++) {
    bf16x8 a = *(const bf16x8*)(wrow + kk * 32);
#pragma unroll
    for (int j = 0; j < 4; j++) {
      bf16x8 bb = *(const bf16x8*)(xp + (size_t)(n0 + j * 16 + lr) * C_N + kk * 32 + g * 8);
      acc[j] = __builtin_amdgcn_mfma_f32_16x16x32_bf16(a, bb, acc[j], 0, 0, 0);
    }
  }
  int cw = c0 + w * 16 + g * 4;
  f32x4 bs = {0.f, 0.f, 0.f, 0.f};
  if (bias) { bs[0] = bias[cw]; bs[1] = bias[cw + 1]; bs[2] = bias[cw + 2]; bs[3] = bias[cw + 3]; }
  float* yp = Yt + (size_t)b * NC;
#pragma unroll
  for (int j = 0; j < 4; j++) {
    int n = n0 + j * 16 + lr;
    f32x4 v = acc[j] + bs;
    *(f32x4*)(yp + (size_t)n * C_N + cw) = v;
  }
}

// ---------------- dual GEMM: yr = Wb1@x + b1r ; y1 = Wb2@x + b11 (shared B reads) ----------------
__global__ __launch_bounds__(256) void gemm_dual_kernel(
    const uint16_t* __restrict__ Wb1, const uint16_t* __restrict__ Wb2,
    const uint16_t* __restrict__ Xb,
    const float* __restrict__ bias1, const float* __restrict__ bias2,
    float* __restrict__ Y1, float* __restrict__ Y2) {
  int b = blockIdx.z;
  int n0 = blockIdx.x * 64;
  int c0 = blockIdx.y * 64;
  int w = threadIdx.x >> 6;
  int l = threadIdx.x & 63;
  int lr = l & 15, g = l >> 4;
  const uint16_t* xp = Xb + (size_t)b * NC;
  f32x4 acc1[4] = {{0.f,0.f,0.f,0.f},{0.f,0.f,0.f,0.f},{0.f,0.f,0.f,0.f},{0.f,0.f,0.f,0.f}};
  f32x4 acc2[4] = {{0.f,0.f,0.f,0.f},{0.f,0.f,0.f,0.f},{0.f,0.f,0.f,0.f},{0.f,0.f,0.f,0.f}};
  const uint16_t* wrow1 = Wb1 + (size_t)(c0 + w * 16 + lr) * C_N + g * 8;
  const uint16_t* wrow2 = Wb2 + (size_t)(c0 + w * 16 + lr) * C_N + g * 8;
#pragma unroll
  for (int kk = 0; kk < 8; kk++) {
    bf16x8 a1 = *(const bf16x8*)(wrow1 + kk * 32);
    bf16x8 a2 = *(const bf16x8*)(wrow2 + kk * 32);
#pragma unroll
    for (int j = 0; j < 4; j++) {
      bf16x8 bb = *(const bf16x8*)(xp + (size_t)(n0 + j * 16 + lr) * C_N + kk * 32 + g * 8);
      acc1[j] = __builtin_amdgcn_mfma_f32_16x16x32_bf16(a1, bb, acc1[j], 0, 0, 0);
      acc2[j] = __builtin_amdgcn_mfma_f32_16x16x32_bf16(a2, bb, acc2[j], 0, 0, 0);
    }
  }
  int cw = c0 + w * 16 + g * 4;
  f32x4 bs1 = { bias1[cw], bias1[cw + 1], bias1[cw + 2], bias1[cw + 3] };
  f32x4 bs2 = { bias2[cw], bias2[cw + 1], bias2[cw + 2], bias2[cw + 3] };
  float* y1p = Y1 + (size_t)b * NC;
  float* y2p = Y2 + (size_t)b * NC;
#pragma unroll
  for (int j = 0; j < 4; j++) {
    int n = n0 + j * 16 + lr;
    f32x4 v1 = acc1[j] + bs1;
    f32x4 v2 = acc2[j] + bs2;
    *(f32x4*)(y1p + (size_t)n * C_N + cw) = v1;
    *(f32x4*)(y2p + (size_t)n * C_N + cw) = v2;
  }
}

// ---------------- GEMM0 + fused q/v epilogue (removes qv pass + feat f32 roundtrip) ----------------
// q = bf16(feat) in (N,C); v = bf16(elu(feat)) in (C,N) via LDS transpose so
// the (C,N) store is coalesced along n (r11 variant, now tested in isolation).
__global__ __launch_bounds__(256) void gemm_qv_kernel(
    const uint16_t* __restrict__ Wb, const uint16_t* __restrict__ Xb,
    uint16_t* __restrict__ qt, uint16_t* __restrict__ vcn) {
  __shared__ uint16_t vlds[64][72]; // [c_local][n_local], pad 72 (9.2 KB)
  int b = blockIdx.z;
  int n0 = blockIdx.x * 64;
  int c0 = blockIdx.y * 64;
  int w = threadIdx.x >> 6;
  int l = threadIdx.x & 63;
  int lr = l & 15, g = l >> 4;
  const uint16_t* xp = Xb + (size_t)b * NC;
  f32x4 acc[4] = {{0.f,0.f,0.f,0.f},{0.f,0.f,0.f,0.f},{0.f,0.f,0.f,0.f},{0.f,0.f,0.f,0.f}};
  const uint16_t* wrow = Wb + (size_t)(c0 + w * 16 + lr) * C_N + g * 8;
#pragma unroll
  for (int kk = 0; kk < 8; kk++) {
    bf16x8 a = *(const bf16x8*)(wrow + kk * 32);
#pragma unroll
    for (int j = 0; j < 4; j++) {
      bf16x8 bb = *(const bf16x8*)(xp + (size_t)(n0 + j * 16 + lr) * C_N + kk * 32 + g * 8);
      acc[j] = __builtin_amdgcn_mfma_f32_16x16x32_bf16(a, bb, acc[j], 0, 0, 0);
    }
  }
  int cl0 = w * 16 + g * 4;        // lane's first local channel
  uint16_t* qb = qt + (size_t)b * NC;
#pragma unroll
  for (int j = 0; j < 4; j++) {
    int n = n0 + j * 16 + lr;
    uint16_t qk4[4];
#pragma unroll
    for (int r = 0; r < 4; r++) {
      float v = acc[j][r];
      qk4[r] = f2bf(v);
      float e = v > 0.f ? v : (__expf(v) - 1.f);
      vlds[cl0 + r][j * 16 + lr] = f2bf(e);
    }
    uint2 pk;
    pk.x = (uint32_t)qk4[0] | ((uint32_t)qk4[1] << 16);
    pk.y = (uint32_t)qk4[2] | ((uint32_t)qk4[3] << 16);
    *(uint2*)(qb + (size_t)n * C_N + c0 + cl0) = pk;
  }
  __syncthreads();
  // coalesced vcn store: thread -> (c row, 16-wide n segment)
  int cl = threadIdx.x >> 2;       // 0..63
  int seg = threadIdx.x & 3;       // 0..3
  uint16_t* vrow = vcn + (size_t)b * NC + (size_t)(c0 + cl) * N_N + n0 + seg * 16;
  *(uint4*)(vrow)     = *(const uint4*)(&vlds[cl][seg * 16]);
  *(uint4*)(vrow + 8) = *(const uint4*)(&vlds[cl][seg * 16 + 8]);
}

// ---------------- FUSED attention: Opart = softmax_part(QK) @ V^T ----------------
// (unchanged from r17 — 96us, eliminates P round-trip; LDS 68KB, 2 blocks/CU)
__global__ __launch_bounds__(256, 2) void attn_fused_kernel(
    const uint16_t* __restrict__ qt, const uint16_t* __restrict__ vcn,
    const float* __restrict__ ea, const int* __restrict__ em,
    float* __restrict__ Opart, float* __restrict__ rowsum, int mlen) {
  __shared__ uint16_t alds[2][32 * 256]; // Q m-tile, 2 x 16 KB
  __shared__ uint16_t vlds[2][256 * 32]; // V tile,   2 x 16 KB
  __shared__ uint16_t plds[64 * 32];     // P bounce, 4 KB
  int b = blockIdx.z;
  int mstart = blockIdx.y * mlen;
  int nb = blockIdx.x * 64;
  int w = threadIdx.x >> 6, l = threadIdx.x & 63;
  int lr = l & 15, g = l >> 4;
  int n = nb + w * 16 + lr;         // this lane's n-row
  const uint16_t* qb = qt + (size_t)b * NC;
  const uint16_t* vb = vcn + (size_t)b * NC;
  const size_t ebase = (size_t)b * N_N * N_N + (size_t)n * N_N;

  bf16x8 qa[8];
#pragma unroll
  for (int kk = 0; kk < 8; kk++)
    qa[kk] = *(const bf16x8*)(qb + (size_t)n * C_N + kk * 32 + g * 8);

  auto STAGE = [&](int t) {
    int m0 = mstart + t * 32;
    uint16_t* abuf = alds[t & 1];
#pragma unroll
    for (int q = 0; q < 4; q++) {
      int chunk = w * 4 + q;                 // 0..15
      int row_local = chunk * 2 + (l >> 5);  // 0..31
      int cb = l & 31;
      int src_cb = cb ^ (row_local & 7);
      const uint16_t* src = qb + (size_t)(m0 + row_local) * C_N + src_cb * 8;
      __builtin_amdgcn_global_load_lds((g1_void*)src, (l3_void*)(abuf + chunk * 512), 16, 0, 0);
    }
    uint16_t* vbuf = vlds[t & 1];
#pragma unroll
    for (int q = 0; q < 4; q++) {
      int c = (w * 4 + q) * 16 + (l >> 2);   // 0..255
      int seg = (l & 3) ^ (c & 3);
      const uint16_t* src = vb + (size_t)c * N_N + m0 + seg * 8;
      __builtin_amdgcn_global_load_lds((g1_void*)src, (l3_void*)(vbuf + (w * 4 + q) * 512), 16, 0, 0);
    }
  };
  auto EDGES = [&](int t, i32x4* em4, f32x4* ea4) {
    int m0 = mstart + t * 32;
    const size_t erow = ebase + m0 + g * 4;
#pragma unroll
    for (int j = 0; j < 2; j++) {
      em4[j] = __builtin_nontemporal_load((const i32x4*)(em + erow + j * 16));
      ea4[j] = __builtin_nontemporal_load((const f32x4*)(ea + erow + j * 16));
    }
  };

  i32x4 emc[2], emn[2]; f32x4 eac[2], ean[2];
  STAGE(0);
  EDGES(0, emc, eac);

  f32x4 accp[4][4];
#pragma unroll
  for (int tt = 0; tt < 4; tt++)
#pragma unroll
    for (int j = 0; j < 4; j++) accp[tt][j] = (f32x4){0.f, 0.f, 0.f, 0.f};
  float rs = 0.f;
  const int NT = mlen / 32;
  int swA = lr & 7;  // Q-tile swizzle key
  int swP = lr & 3;  // P/V swizzle key
  for (int t = 0; t < NT; ++t) {
    asm volatile("s_waitcnt vmcnt(4)" ::: "memory");
    __builtin_amdgcn_s_barrier();
    __builtin_amdgcn_sched_barrier(0);
    if (t + 1 < NT) { STAGE(t + 1); EDGES(t + 1, emn, ean); }
    const uint16_t* abuf = alds[t & 1];
    f32x4 acc[2] = {{0.f,0.f,0.f,0.f},{0.f,0.f,0.f,0.f}};
#pragma unroll
    for (int kk = 0; kk < 8; kk++) {
#pragma unroll
      for (int j = 0; j < 2; j++) {
        int cb = (kk * 4 + g) ^ swA;
        bf16x8 qm = *(const bf16x8*)(abuf + (j * 16 + lr) * 256 + cb * 8);
        acc[j] = __builtin_amdgcn_mfma_f32_16x16x32_bf16(qm, qa[kk], acc[j], 0, 0, 0);
      }
    }
#pragma unroll
    for (int j = 0; j < 2; j++) {
      uint16_t pk[4];
#pragma unroll
      for (int r = 0; r < 4; r++) {
        float p = emc[j][r] ? __expf(eac[j][r] * acc[j][r] * INV_T) : 0.f;
        rs += p;
        pk[r] = f2bf(p);
      }
      uint2 st;
      st.x = (uint32_t)pk[0] | ((uint32_t)pk[1] << 16);
      st.y = (uint32_t)pk[2] | ((uint32_t)pk[3] << 16);
      *(uint2*)(plds + (w * 16 + lr) * 32 + (((2 * j + (g >> 1)) ^ swP) * 8) + (g & 1) * 4) = st;
    }
    emc[0] = emn[0]; emc[1] = emn[1];
    eac[0] = ean[0]; eac[1] = ean[1];
    __builtin_amdgcn_s_barrier();
    __builtin_amdgcn_sched_barrier(0);
    const uint16_t* vbuf = vlds[t & 1];
    bf16x8 bv[4], av[4];
#pragma unroll
    for (int j = 0; j < 4; j++)
      bv[j] = *(const bf16x8*)(plds + (j * 16 + lr) * 32 + ((g ^ swP) * 8));
#pragma unroll
    for (int tt = 0; tt < 4; tt++)
      av[tt] = *(const bf16x8*)(vbuf + (w * 64 + tt * 16 + lr) * 32 + ((g ^ swP) * 8));
#pragma unroll
    for (int tt = 0; tt < 4; tt++)
#pragma unroll
      for (int j = 0; j < 4; j++)
        accp[tt][j] = __builtin_amdgcn_mfma_f32_16x16x32_bf16(av[tt], bv[j], accp[tt][j], 0, 0, 0);
    __builtin_amdgcn_sched_barrier(0);
  }
  float* op = Opart + ((size_t)blockIdx.y * B_N + b) * NC;
#pragma unroll
  for (int tt = 0; tt < 4; tt++) {
    int cw = w * 64 + tt * 16 + g * 4;
#pragma unroll
    for (int j = 0; j < 4; j++) {
      int nn = nb + j * 16 + lr;
      *(f32x4*)(op + (size_t)nn * C_N + cw) = accp[tt][j];
    }
  }
  rs += __shfl_xor(rs, 16, 64);
  rs += __shfl_xor(rs, 32, 64);
  if (l < 16)
    atomicAdd(&rowsum[(size_t)b * N_N + n], rs);
}

// ---------------- combine split-K: val = sum(Opart)/rowsum; per-batch IN stats ----------------
__global__ __launch_bounds__(256) void combine_kernel(
    const float* __restrict__ Op, const float* __restrict__ rowsum,
    float* __restrict__ val, float* __restrict__ vstats, int split) {
  size_t idx = ((size_t)blockIdx.x * 256 + threadIdx.x) * 4;
  int b = (int)(idx / NC);
  size_t inb = idx - (size_t)b * NC;
  size_t n = inb / C_N;
  f32x4 acc = {0.f, 0.f, 0.f, 0.f};
  for (int s = 0; s < split; s++)
    acc += *(const f32x4*)(Op + (size_t)(s * B_N + b) * NC + inb);
  float lt = rowsum[(size_t)b * N_N + n];
  float invl = lt > 0.f ? 1.f / lt : 0.f;
  acc *= invl;
  *(f32x4*)(val + idx) = acc;
  float s1 = acc[0] + acc[1] + acc[2] + acc[3];
  float s2 = acc[0]*acc[0] + acc[1]*acc[1] + acc[2]*acc[2] + acc[3]*acc[3];
  for (int off = 32; off; off >>= 1) { s1 += __shfl_down(s1, off, 64); s2 += __shfl_down(s2, off, 64); }
  __shared__ float r1[4], r2[4];
  int w = threadIdx.x >> 6;
  if ((threadIdx.x & 63) == 0) { r1[w] = s1; r2[w] = s2; }
  __syncthreads();
  if (threadIdx.x == 0) {
    atomicAdd(&vstats[b * 2],     r1[0] + r1[1] + r1[2] + r1[3]);
    atomicAdd(&vstats[b * 2 + 1], r2[0] + r2[1] + r2[2] + r2[3]);
  }
}

// ---------------- feat_attn = IN(val) + x -> bf16 (in place over xtb) ----------------
__global__ __launch_bounds__(256) void fa_kernel(
    const float* __restrict__ val, const float* __restrict__ vstats,
    uint16_t* __restrict__ fab) {
  size_t idx = ((size_t)blockIdx.x * 256 + threadIdx.x) * 4;
  int b = (int)(idx / NC);
  float mean = vstats[b * 2] * (1.f / NC);
  float var = vstats[b * 2 + 1] * (1.f / NC) - mean * mean;
  float inv = rsqrtf(var + EPS_);
  f32x4 v = *(const f32x4*)(val + idx);
  uint2 xr = *(const uint2*)(fab + idx);
  float xv[4] = { bf2f((uint16_t)(xr.x & 0xffff)), bf2f((uint16_t)(xr.x >> 16)),
                  bf2f((uint16_t)(xr.y & 0xffff)), bf2f((uint16_t)(xr.y >> 16)) };
  uint16_t ov[4];
#pragma unroll
  for (int j = 0; j < 4; j++) ov[j] = f2bf((v[j] - mean) * inv + xv[j]);
  uint2 pk;
  pk.x = (uint32_t)ov[0] | ((uint32_t)ov[1] << 16);
  pk.y = (uint32_t)ov[2] | ((uint32_t)ov[3] << 16);
  *(uint2*)(fab + idx) = pk;
}

// ---------------- per-column sum/sumsq for TWO buffers, 16 rows/block ----------------
__global__ __launch_bounds__(256) void colstats_dual_kernel(
    const float* __restrict__ Ya, float* __restrict__ outa,
    const float* __restrict__ Yb, float* __restrict__ outb) {
  const float* Y = blockIdx.y ? Yb : Ya;
  float* out = blockIdx.y ? outb : outa;
  int perBatch = blockIdx.y;
  int c = threadIdx.x;
  size_t r0 = (size_t)blockIdx.x * 16;
  float s1 = 0.f, s2 = 0.f;
  const float* base = Y + r0 * C_N + c;
  for (int r = 0; r < 16; r++) { float v = base[(size_t)r * C_N]; s1 += v; s2 += v * v; }
  int b = perBatch ? (int)(r0 / N_N) : 0;
  atomicAdd(&out[(b * C_N + c) * 2], s1);
  atomicAdd(&out[(b * C_N + c) * 2 + 1], s2);
}

// ---------------- per-column (channel) sum/sumsq, 16 rows/block ----------------
__global__ __launch_bounds__(256) void colstats_kernel(
    const float* __restrict__ Y, float* __restrict__ out, int perBatch) {
  int c = threadIdx.x;
  size_t r0 = (size_t)blockIdx.x * 16;
  float s1 = 0.f, s2 = 0.f;
  const float* base = Y + r0 * C_N + c;
  for (int r = 0; r < 16; r++) { float v = base[(size_t)r * C_N]; s1 += v; s2 += v * v; }
  int b = perBatch ? (int)(r0 / N_N) : 0;
  atomicAdd(&out[(b * C_N + c) * 2], s1);
  atomicAdd(&out[(b * C_N + c) * 2 + 1], s2);
}

// ---------------- h = relu(BN(IN(y1))) -> bf16 ; BN of IN is closed-form ----------------
__global__ __launch_bounds__(256) void h_kernel(
    const float* __restrict__ y1, const float* __restrict__ st,
    const float* __restrict__ bw, const float* __restrict__ bb, uint16_t* __restrict__ h) {
  size_t idx = ((size_t)blockIdx.x * 256 + threadIdx.x) * 4;
  int b = (int)(idx / NC);
  int c = (int)(idx % C_N);
  f32x4 y = *(const f32x4*)(y1 + idx);
  uint16_t ov[4];
#pragma unroll
  for (int j = 0; j < 4; j++) {
    int cc = c + j;
    float m0 = st[(0 * C_N + cc) * 2] * (1.f / N_N);
    float v0 = st[(0 * C_N + cc) * 2 + 1] * (1.f / N_N) - m0 * m0;
    float m1 = st[(1 * C_N + cc) * 2] * (1.f / N_N);
    float v1 = st[(1 * C_N + cc) * 2 + 1] * (1.f / N_N) - m1 * m1;
    float mb = b ? m1 : m0, vb = b ? v1 : v0;
    float vc = 0.5f * (v0 / (v0 + EPS_) + v1 / (v1 + EPS_)); // BN var of IN output
    float val = (y[j] - mb) * rsqrtf(vb + EPS_) * rsqrtf(vc + EPS_) * bw[cc] + bb[cc];
    ov[j] = f2bf(fmaxf(val, 0.f));
  }
  uint2 pk;
  pk.x = (uint32_t)ov[0] | ((uint32_t)ov[1] << 16);
  pk.y = (uint32_t)ov[2] | ((uint32_t)ov[3] << 16);
  *(uint2*)(h + idx) = pk;
}

// ---------------- final: out[b][c][n] = relu( BN2(IN2(y2)) + BN_r(y_r) ) ----------------
__global__ __launch_bounds__(256) void final_kernel(
    const float* __restrict__ y2, const float* __restrict__ yr,
    const float* __restrict__ st2, const float* __restrict__ strr,
    const float* __restrict__ g2, const float* __restrict__ be2,
    const float* __restrict__ gr, const float* __restrict__ ber, float* __restrict__ out) {
  __shared__ float t[32][33];
  int b = blockIdx.z;
  int n0 = blockIdx.x * 32, c0 = blockIdx.y * 32;
  int tc = threadIdx.x & 31, tr = threadIdx.x >> 5;
  int c = c0 + tc;
  float m20 = st2[(0 * C_N + c) * 2] * (1.f / N_N);
  float v20 = st2[(0 * C_N + c) * 2 + 1] * (1.f / N_N) - m20 * m20;
  float m21 = st2[(1 * C_N + c) * 2] * (1.f / N_N);
  float v21 = st2[(1 * C_N + c) * 2 + 1] * (1.f / N_N) - m21 * m21;
  float mb = b ? m21 : m20, vb = b ? v21 : v20;
  float inb = rsqrtf(vb + EPS_);
  float vc2 = 0.5f * (v20 / (v20 + EPS_) + v21 / (v21 + EPS_));
  float sc2 = rsqrtf(vc2 + EPS_) * g2[c];
  float mr = strr[c * 2] * (1.f / (B_N * N_N));
  float vr = strr[c * 2 + 1] * (1.f / (B_N * N_N)) - mr * mr;
  float scr = rsqrtf(vr + EPS_) * gr[c];
  const float* y2b = y2 + (size_t)b * NC;
  const float* yrb = yr + (size_t)b * NC;
#pragma unroll
  for (int pp = 0; pp < 4; pp++) {
    int r = tr + pp * 8;
    size_t off = (size_t)(n0 + r) * C_N + c;
    float a = (y2b[off] - mb) * inb * sc2 + be2[c];
    float x1 = (yrb[off] - mr) * scr + ber[c];
    t[r][tc] = fmaxf(a + x1, 0.f);
  }
  __syncthreads();
  float* ob = out + (size_t)b * C_N * N_N;
#pragma unroll
  for (int pp = 0; pp < 4; pp++) {
    int r = tr + pp * 8;
    ob[(size_t)(c0 + r) * N_N + n0 + tc] = t[tc][r];
  }
}

extern "C" void kernel_launch(void* const* d_in, const int* in_sizes, int n_in,
                              void* d_out, int out_size, void* d_ws, size_t ws_size,
                              hipStream_t stream) {
  (void)in_sizes; (void)n_in; (void)out_size;
  const float* x    = (const float*)d_in[0];
  const int*   em   = (const int*)  d_in[1];
  const float* ea   = (const float*)d_in[2];
  const float* lw   = (const float*)d_in[3];
  const float* wr   = (const float*)d_in[4];
  const float* br   = (const float*)d_in[5];
  const float* bnrw = (const float*)d_in[6];
  const float* bnrb = (const float*)d_in[7];
  const float* w1   = (const float*)d_in[8];
  const float* b1   = (const float*)d_in[9];
  const float* bn1w = (const float*)d_in[10];
  const float* bn1b = (const float*)d_in[11];
  const float* w2   = (const float*)d_in[12];
  const float* b2   = (const float*)d_in[13];
  const float* bn2w = (const float*)d_in[14];
  const float* bn2b = (const float*)d_in[15];

  char* p = (char*)d_ws;
  auto alloc = [&](size_t bytes) -> char* {
    char* r = p; p += (bytes + 255) & ~(size_t)255; return r;
  };
  // persistent small buffers
  uint16_t* xtb = (uint16_t*)alloc(2ULL * B_N * NC);   // x_t bf16 -> feat_attn bf16 (in place)
  uint16_t* qt  = (uint16_t*)alloc(2ULL * B_N * NC);   // q bf16 -> h bf16
  uint16_t* vcn = (uint16_t*)alloc(2ULL * B_N * NC);   // v bf16 (C,N)
  uint16_t* wb0 = (uint16_t*)alloc(2ULL * C_N * C_N);
  uint16_t* wb1 = (uint16_t*)alloc(2ULL * C_N * C_N);
  uint16_t* wb2 = (uint16_t*)alloc(2ULL * C_N * C_N);
  uint16_t* wb3 = (uint16_t*)alloc(2ULL * C_N * C_N);
  constexpr int STATS_F = 4 + 512 + 1024 + 1024;
  constexpr int RS_F = B_N * N_N;
  float* stats = (float*)alloc(sizeof(float) * (STATS_F + RS_F));
  float* vstats = stats;
  float* strr   = stats + 4;
  float* st1    = strr + 512;
  float* st2    = st1 + 1024;
  float* rowsum = stats + STATS_F;
  // big region (reused): feat / yr / y2 / y1
  float* feat = (float*)alloc(sizeof(float) * (size_t)B_N * NC);
  float* yr   = (float*)alloc(sizeof(float) * (size_t)B_N * NC);
  float* y2   = (float*)alloc(sizeof(float) * (size_t)B_N * NC);
  float* y1   = (float*)alloc(sizeof(float) * (size_t)B_N * NC);
  // split-m partials for fused attention
  size_t fixed = (size_t)(p - (char*)d_ws);
  size_t partsz = sizeof(float) * (size_t)B_N * NC;      // 8 MB per split
  int SPLITK = 4;
  while (SPLITK > 1 && fixed + (size_t)SPLITK * partsz > ws_size) SPLITK >>= 1;
  float* Opart = (float*)alloc((size_t)SPLITK * partsz);

  (void)hipMemsetAsync(stats, 0, sizeof(float) * (STATS_F + RS_F), stream);

  cast_w_kernel<<<dim3(C_N * C_N / 256, 4, 1), 256, 0, stream>>>(lw, wr, w1, w2, wb0, wb1, wb2, wb3);
  transpose_x_kernel<<<dim3(C_N / 32, N_N / 32, B_N), 256, 0, stream>>>(x, xtb);
  gemm_qv_kernel<<<dim3(N_N / 64, C_N / 64, B_N), 256, 0, stream>>>(wb0, xtb, qt, vcn);
  attn_fused_kernel<<<dim3(N_N / 64, SPLITK, B_N), 256, 0, stream>>>(
      qt, vcn, ea, em, Opart, rowsum, N_N / SPLITK);
  combine_kernel<<<dim3((size_t)B_N * NC / 1024), 256, 0, stream>>>(Opart, rowsum, feat, vstats, SPLITK);
  fa_kernel<<<dim3((size_t)B_N * NC / 1024), 256, 0, stream>>>(feat, vstats, xtb);
  gemm_dual_kernel<<<dim3(N_N / 64, C_N / 64, B_N), 256, 0, stream>>>(wb1, wb2, xtb, br, b1, yr, y1);
  colstats_dual_kernel<<<dim3(B_N * N_N / 16, 2), 256, 0, stream>>>(yr, strr, y1, st1);
  h_kernel<<<dim3((size_t)B_N * NC / 1024), 256, 0, stream>>>(y1, st1, bn1w, bn1b, qt);
  gemm_kernel<<<dim3(N_N / 64, C_N / 64, B_N), 256, 0, stream>>>(wb3, qt, b2, y2);
  colstats_kernel<<<dim3(B_N * N_N / 16), 256, 0, stream>>>(y2, st2, 1);
  final_kernel<<<dim3(N_N / 32, C_N / 32, B_N), 256, 0, stream>>>(
      y2, yr, st2, strr, bn2w, bn2b, bnrw, bnrb, (float*)d_out);
}

// Round 19
// 241.689 us; speedup vs baseline: 1.1663x; 1.1663x over previous
//
#include <hip/hip_runtime.h>
#include <hip/hip_bf16.h>
#include <cstdint>
#include <cstddef>

// Problem constants (match reference)
constexpr int B_N = 2;
constexpr int C_N = 256;
constexpr int N_N = 4096;
constexpr int NC  = N_N * C_N;        // 1,048,576
constexpr float EPS_  = 1e-5f;
constexpr float INV_T = 1.0f / 16.0f; // 1/sqrt(C)

using bf16x8 = __attribute__((ext_vector_type(8))) __bf16;
using f32x4  = __attribute__((ext_vector_type(4))) float;
using i32x4  = __attribute__((ext_vector_type(4))) int;

typedef __attribute__((address_space(1))) const void g1_void;
typedef __attribute__((address_space(3))) void l3_void;

__device__ __forceinline__ uint16_t f2bf(float f) {
  uint32_t u = __builtin_bit_cast(uint32_t, f);
  u += 0x7fffu + ((u >> 16) & 1u);
  return (uint16_t)(u >> 16);
}
__device__ __forceinline__ float bf2f(uint16_t h) {
  return __builtin_bit_cast(float, (uint32_t)h << 16);
}

// ---------------- weight cast: 4 (C,C) f32 -> bf16 ----------------
__global__ __launch_bounds__(256) void cast_w_kernel(
    const float* __restrict__ w0, const float* __restrict__ w1,
    const float* __restrict__ w2, const float* __restrict__ w3,
    uint16_t* __restrict__ o0, uint16_t* __restrict__ o1,
    uint16_t* __restrict__ o2, uint16_t* __restrict__ o3) {
  int i = blockIdx.x * 256 + threadIdx.x;
  int m = blockIdx.y;
  const float* s = (m == 0) ? w0 : (m == 1) ? w1 : (m == 2) ? w2 : w3;
  uint16_t* d = (m == 0) ? o0 : (m == 1) ? o1 : (m == 2) ? o2 : o3;
  d[i] = f2bf(s[i]);
}

// ---------------- transpose x (B,C,N) -> x_t bf16 (B,N,C) ----------------
__global__ __launch_bounds__(256) void transpose_x_kernel(
    const float* __restrict__ x, uint16_t* __restrict__ xtb) {
  __shared__ float tile[32][33];
  int b = blockIdx.z;
  int c0 = blockIdx.x * 32, n0 = blockIdx.y * 32;
  int tc = threadIdx.x & 31, tr = threadIdx.x >> 5;
  const float* xb = x + (size_t)b * C_N * N_N;
#pragma unroll
  for (int pp = 0; pp < 4; pp++) {
    int r = tr + pp * 8;
    tile[r][tc] = xb[(size_t)(c0 + r) * N_N + n0 + tc];
  }
  __syncthreads();
  uint16_t* xtbp = xtb + (size_t)b * NC;
#pragma unroll
  for (int pp = 0; pp < 4; pp++) {
    int r = tr + pp * 8;
    xtbp[(size_t)(n0 + r) * C_N + c0 + tc] = f2bf(tile[tc][r]);
  }
}

// ---------------- GEMM: Yt[b][n][c_out] = sum_k Wb[c_out][k]*Xb[b][n][k] + bias ----------------
__global__ __launch_bounds__(256) void gemm_kernel(
    const uint16_t* __restrict__ Wb, const uint16_t* __restrict__ Xb,
    const float* __restrict__ bias, float* __restrict__ Yt) {
  int b = blockIdx.z;
  int n0 = blockIdx.x * 64;
  int c0 = blockIdx.y * 64;
  int w = threadIdx.x >> 6;
  int l = threadIdx.x & 63;
  int lr = l & 15, g = l >> 4;
  const uint16_t* xp = Xb + (size_t)b * NC;
  f32x4 acc[4] = {{0.f,0.f,0.f,0.f},{0.f,0.f,0.f,0.f},{0.f,0.f,0.f,0.f},{0.f,0.f,0.f,0.f}};
  const uint16_t* wrow = Wb + (size_t)(c0 + w * 16 + lr) * C_N + g * 8;
#pragma unroll
  for (int kk = 0; kk < 8; kk++) {
    bf16x8 a = *(const bf16x8*)(wrow + kk * 32);
#pragma unroll
    for (int j = 0; j < 4; j++) {
      bf16x8 bb = *(const bf16x8*)(xp + (size_t)(n0 + j * 16 + lr) * C_N + kk * 32 + g * 8);
      acc[j] = __builtin_amdgcn_mfma_f32_16x16x32_bf16(a, bb, acc[j], 0, 0, 0);
    }
  }
  int cw = c0 + w * 16 + g * 4;
  f32x4 bs = {0.f, 0.f, 0.f, 0.f};
  if (bias) { bs[0] = bias[cw]; bs[1] = bias[cw + 1]; bs[2] = bias[cw + 2]; bs[3] = bias[cw + 3]; }
  float* yp = Yt + (size_t)b * NC;
#pragma unroll
  for (int j = 0; j < 4; j++) {
    int n = n0 + j * 16 + lr;
    f32x4 v = acc[j] + bs;
    *(f32x4*)(yp + (size_t)n * C_N + cw) = v;
  }
}

// ---------------- dual GEMM: yr = Wb1@x + b1r ; y1 = Wb2@x + b11 (shared B reads) ----------------
__global__ __launch_bounds__(256) void gemm_dual_kernel(
    const uint16_t* __restrict__ Wb1, const uint16_t* __restrict__ Wb2,
    const uint16_t* __restrict__ Xb,
    const float* __restrict__ bias1, const float* __restrict__ bias2,
    float* __restrict__ Y1, float* __restrict__ Y2) {
  int b = blockIdx.z;
  int n0 = blockIdx.x * 64;
  int c0 = blockIdx.y * 64;
  int w = threadIdx.x >> 6;
  int l = threadIdx.x & 63;
  int lr = l & 15, g = l >> 4;
  const uint16_t* xp = Xb + (size_t)b * NC;
  f32x4 acc1[4] = {{0.f,0.f,0.f,0.f},{0.f,0.f,0.f,0.f},{0.f,0.f,0.f,0.f},{0.f,0.f,0.f,0.f}};
  f32x4 acc2[4] = {{0.f,0.f,0.f,0.f},{0.f,0.f,0.f,0.f},{0.f,0.f,0.f,0.f},{0.f,0.f,0.f,0.f}};
  const uint16_t* wrow1 = Wb1 + (size_t)(c0 + w * 16 + lr) * C_N + g * 8;
  const uint16_t* wrow2 = Wb2 + (size_t)(c0 + w * 16 + lr) * C_N + g * 8;
#pragma unroll
  for (int kk = 0; kk < 8; kk++) {
    bf16x8 a1 = *(const bf16x8*)(wrow1 + kk * 32);
    bf16x8 a2 = *(const bf16x8*)(wrow2 + kk * 32);
#pragma unroll
    for (int j = 0; j < 4; j++) {
      bf16x8 bb = *(const bf16x8*)(xp + (size_t)(n0 + j * 16 + lr) * C_N + kk * 32 + g * 8);
      acc1[j] = __builtin_amdgcn_mfma_f32_16x16x32_bf16(a1, bb, acc1[j], 0, 0, 0);
      acc2[j] = __builtin_amdgcn_mfma_f32_16x16x32_bf16(a2, bb, acc2[j], 0, 0, 0);
    }
  }
  int cw = c0 + w * 16 + g * 4;
  f32x4 bs1 = { bias1[cw], bias1[cw + 1], bias1[cw + 2], bias1[cw + 3] };
  f32x4 bs2 = { bias2[cw], bias2[cw + 1], bias2[cw + 2], bias2[cw + 3] };
  float* y1p = Y1 + (size_t)b * NC;
  float* y2p = Y2 + (size_t)b * NC;
#pragma unroll
  for (int j = 0; j < 4; j++) {
    int n = n0 + j * 16 + lr;
    f32x4 v1 = acc1[j] + bs1;
    f32x4 v2 = acc2[j] + bs2;
    *(f32x4*)(y1p + (size_t)n * C_N + cw) = v1;
    *(f32x4*)(y2p + (size_t)n * C_N + cw) = v2;
  }
}

// ---------------- q(bf16, N,C) + v=elu (bf16, C,N) from feat (f32, N,C) ----------------
__global__ __launch_bounds__(256) void qv_kernel(
    const float* __restrict__ feat, uint16_t* __restrict__ qt, uint16_t* __restrict__ vcn) {
  __shared__ float tile[32][33];
  int b = blockIdx.z;
  int n0 = blockIdx.x * 32, c0 = blockIdx.y * 32;
  int tc = threadIdx.x & 31, tr = threadIdx.x >> 5;
  const float* fb = feat + (size_t)b * NC;
  uint16_t* qb = qt + (size_t)b * NC;
#pragma unroll
  for (int pp = 0; pp < 4; pp++) {
    int r = tr + pp * 8;
    float v = fb[(size_t)(n0 + r) * C_N + c0 + tc];
    qb[(size_t)(n0 + r) * C_N + c0 + tc] = f2bf(v);
    tile[r][tc] = v;
  }
  __syncthreads();
  uint16_t* vbp = vcn + (size_t)b * NC; // (C,N)
#pragma unroll
  for (int pp = 0; pp < 4; pp++) {
    int r = tr + pp * 8;
    float v = tile[tc][r]; // feat[n0+tc][c0+r]
    float e = v > 0.f ? v : (__expf(v) - 1.f);
    vbp[(size_t)(c0 + r) * N_N + n0 + tc] = f2bf(e);
  }
}

// ---------------- FUSED attention: Opart = softmax_part(QK) @ V^T ----------------
// (r17 config — eliminates P round-trip; LDS 68KB, 2 blocks/CU, 96us)
__global__ __launch_bounds__(256, 2) void attn_fused_kernel(
    const uint16_t* __restrict__ qt, const uint16_t* __restrict__ vcn,
    const float* __restrict__ ea, const int* __restrict__ em,
    float* __restrict__ Opart, float* __restrict__ rowsum, int mlen) {
  __shared__ uint16_t alds[2][32 * 256]; // Q m-tile, 2 x 16 KB
  __shared__ uint16_t vlds[2][256 * 32]; // V tile,   2 x 16 KB
  __shared__ uint16_t plds[64 * 32];     // P bounce, 4 KB
  int b = blockIdx.z;
  int mstart = blockIdx.y * mlen;
  int nb = blockIdx.x * 64;
  int w = threadIdx.x >> 6, l = threadIdx.x & 63;
  int lr = l & 15, g = l >> 4;
  int n = nb + w * 16 + lr;         // this lane's n-row
  const uint16_t* qb = qt + (size_t)b * NC;
  const uint16_t* vb = vcn + (size_t)b * NC;
  const size_t ebase = (size_t)b * N_N * N_N + (size_t)n * N_N;

  bf16x8 qa[8];
#pragma unroll
  for (int kk = 0; kk < 8; kk++)
    qa[kk] = *(const bf16x8*)(qb + (size_t)n * C_N + kk * 32 + g * 8);

  auto STAGE = [&](int t) {
    int m0 = mstart + t * 32;
    uint16_t* abuf = alds[t & 1];
#pragma unroll
    for (int q = 0; q < 4; q++) {
      int chunk = w * 4 + q;                 // 0..15
      int row_local = chunk * 2 + (l >> 5);  // 0..31
      int cb = l & 31;
      int src_cb = cb ^ (row_local & 7);
      const uint16_t* src = qb + (size_t)(m0 + row_local) * C_N + src_cb * 8;
      __builtin_amdgcn_global_load_lds((g1_void*)src, (l3_void*)(abuf + chunk * 512), 16, 0, 0);
    }
    uint16_t* vbuf = vlds[t & 1];
#pragma unroll
    for (int q = 0; q < 4; q++) {
      int c = (w * 4 + q) * 16 + (l >> 2);   // 0..255
      int seg = (l & 3) ^ (c & 3);
      const uint16_t* src = vb + (size_t)c * N_N + m0 + seg * 8;
      __builtin_amdgcn_global_load_lds((g1_void*)src, (l3_void*)(vbuf + (w * 4 + q) * 512), 16, 0, 0);
    }
  };
  auto EDGES = [&](int t, i32x4* em4, f32x4* ea4) {
    int m0 = mstart + t * 32;
    const size_t erow = ebase + m0 + g * 4;
#pragma unroll
    for (int j = 0; j < 2; j++) {
      em4[j] = __builtin_nontemporal_load((const i32x4*)(em + erow + j * 16));
      ea4[j] = __builtin_nontemporal_load((const f32x4*)(ea + erow + j * 16));
    }
  };

  i32x4 emc[2], emn[2]; f32x4 eac[2], ean[2];
  STAGE(0);
  EDGES(0, emc, eac);

  f32x4 accp[4][4];
#pragma unroll
  for (int tt = 0; tt < 4; tt++)
#pragma unroll
    for (int j = 0; j < 4; j++) accp[tt][j] = (f32x4){0.f, 0.f, 0.f, 0.f};
  float rs = 0.f;
  const int NT = mlen / 32;
  int swA = lr & 7;  // Q-tile swizzle key
  int swP = lr & 3;  // P/V swizzle key
  for (int t = 0; t < NT; ++t) {
    asm volatile("s_waitcnt vmcnt(4)" ::: "memory");
    __builtin_amdgcn_s_barrier();
    __builtin_amdgcn_sched_barrier(0);
    if (t + 1 < NT) { STAGE(t + 1); EDGES(t + 1, emn, ean); }
    const uint16_t* abuf = alds[t & 1];
    f32x4 acc[2] = {{0.f,0.f,0.f,0.f},{0.f,0.f,0.f,0.f}};
#pragma unroll
    for (int kk = 0; kk < 8; kk++) {
#pragma unroll
      for (int j = 0; j < 2; j++) {
        int cb = (kk * 4 + g) ^ swA;
        bf16x8 qm = *(const bf16x8*)(abuf + (j * 16 + lr) * 256 + cb * 8);
        acc[j] = __builtin_amdgcn_mfma_f32_16x16x32_bf16(qm, qa[kk], acc[j], 0, 0, 0);
      }
    }
#pragma unroll
    for (int j = 0; j < 2; j++) {
      uint16_t pk[4];
#pragma unroll
      for (int r = 0; r < 4; r++) {
        float p = emc[j][r] ? __expf(eac[j][r] * acc[j][r] * INV_T) : 0.f;
        rs += p;
        pk[r] = f2bf(p);
      }
      uint2 st;
      st.x = (uint32_t)pk[0] | ((uint32_t)pk[1] << 16);
      st.y = (uint32_t)pk[2] | ((uint32_t)pk[3] << 16);
      *(uint2*)(plds + (w * 16 + lr) * 32 + (((2 * j + (g >> 1)) ^ swP) * 8) + (g & 1) * 4) = st;
    }
    emc[0] = emn[0]; emc[1] = emn[1];
    eac[0] = ean[0]; eac[1] = ean[1];
    __builtin_amdgcn_s_barrier();
    __builtin_amdgcn_sched_barrier(0);
    const uint16_t* vbuf = vlds[t & 1];
    bf16x8 bv[4], av[4];
#pragma unroll
    for (int j = 0; j < 4; j++)
      bv[j] = *(const bf16x8*)(plds + (j * 16 + lr) * 32 + ((g ^ swP) * 8));
#pragma unroll
    for (int tt = 0; tt < 4; tt++)
      av[tt] = *(const bf16x8*)(vbuf + (w * 64 + tt * 16 + lr) * 32 + ((g ^ swP) * 8));
#pragma unroll
    for (int tt = 0; tt < 4; tt++)
#pragma unroll
      for (int j = 0; j < 4; j++)
        accp[tt][j] = __builtin_amdgcn_mfma_f32_16x16x32_bf16(av[tt], bv[j], accp[tt][j], 0, 0, 0);
    __builtin_amdgcn_sched_barrier(0);
  }
  float* op = Opart + ((size_t)blockIdx.y * B_N + b) * NC;
#pragma unroll
  for (int tt = 0; tt < 4; tt++) {
    int cw = w * 64 + tt * 16 + g * 4;
#pragma unroll
    for (int j = 0; j < 4; j++) {
      int nn = nb + j * 16 + lr;
      *(f32x4*)(op + (size_t)nn * C_N + cw) = accp[tt][j];
    }
  }
  rs += __shfl_xor(rs, 16, 64);
  rs += __shfl_xor(rs, 32, 64);
  if (l < 16)
    atomicAdd(&rowsum[(size_t)b * N_N + n], rs);
}

// ---------------- combine split-K: val = sum(Opart)/rowsum; per-batch IN stats ----------------
__global__ __launch_bounds__(256) void combine_kernel(
    const float* __restrict__ Op, const float* __restrict__ rowsum,
    float* __restrict__ val, float* __restrict__ vstats, int split) {
  size_t idx = ((size_t)blockIdx.x * 256 + threadIdx.x) * 4;
  int b = (int)(idx / NC);
  size_t inb = idx - (size_t)b * NC;
  size_t n = inb / C_N;
  f32x4 acc = {0.f, 0.f, 0.f, 0.f};
  for (int s = 0; s < split; s++)
    acc += *(const f32x4*)(Op + (size_t)(s * B_N + b) * NC + inb);
  float lt = rowsum[(size_t)b * N_N + n];
  float invl = lt > 0.f ? 1.f / lt : 0.f;
  acc *= invl;
  *(f32x4*)(val + idx) = acc;
  float s1 = acc[0] + acc[1] + acc[2] + acc[3];
  float s2 = acc[0]*acc[0] + acc[1]*acc[1] + acc[2]*acc[2] + acc[3]*acc[3];
  for (int off = 32; off; off >>= 1) { s1 += __shfl_down(s1, off, 64); s2 += __shfl_down(s2, off, 64); }
  __shared__ float r1[4], r2[4];
  int w = threadIdx.x >> 6;
  if ((threadIdx.x & 63) == 0) { r1[w] = s1; r2[w] = s2; }
  __syncthreads();
  if (threadIdx.x == 0) {
    atomicAdd(&vstats[b * 2],     r1[0] + r1[1] + r1[2] + r1[3]);
    atomicAdd(&vstats[b * 2 + 1], r2[0] + r2[1] + r2[2] + r2[3]);
  }
}

// ---------------- feat_attn = IN(val) + x -> bf16 (in place over xtb) ----------------
__global__ __launch_bounds__(256) void fa_kernel(
    const float* __restrict__ val, const float* __restrict__ vstats,
    uint16_t* __restrict__ fab) {
  size_t idx = ((size_t)blockIdx.x * 256 + threadIdx.x) * 4;
  int b = (int)(idx / NC);
  float mean = vstats[b * 2] * (1.f / NC);
  float var = vstats[b * 2 + 1] * (1.f / NC) - mean * mean;
  float inv = rsqrtf(var + EPS_);
  f32x4 v = *(const f32x4*)(val + idx);
  uint2 xr = *(const uint2*)(fab + idx);
  float xv[4] = { bf2f((uint16_t)(xr.x & 0xffff)), bf2f((uint16_t)(xr.x >> 16)),
                  bf2f((uint16_t)(xr.y & 0xffff)), bf2f((uint16_t)(xr.y >> 16)) };
  uint16_t ov[4];
#pragma unroll
  for (int j = 0; j < 4; j++) ov[j] = f2bf((v[j] - mean) * inv + xv[j]);
  uint2 pk;
  pk.x = (uint32_t)ov[0] | ((uint32_t)ov[1] << 16);
  pk.y = (uint32_t)ov[2] | ((uint32_t)ov[3] << 16);
  *(uint2*)(fab + idx) = pk;
}

// ---------------- per-column sum/sumsq for TWO buffers, 64 rows/block ----------------
__global__ __launch_bounds__(256) void colstats_dual_kernel(
    const float* __restrict__ Ya, float* __restrict__ outa,
    const float* __restrict__ Yb, float* __restrict__ outb) {
  const float* Y = blockIdx.y ? Yb : Ya;
  float* out = blockIdx.y ? outb : outa;
  int perBatch = blockIdx.y;
  int c = threadIdx.x;
  size_t r0 = (size_t)blockIdx.x * 64;
  float s1 = 0.f, s2 = 0.f;
  const float* base = Y + r0 * C_N + c;
  for (int r = 0; r < 64; r++) { float v = base[(size_t)r * C_N]; s1 += v; s2 += v * v; }
  int b = perBatch ? (int)(r0 / N_N) : 0;
  atomicAdd(&out[(b * C_N + c) * 2], s1);
  atomicAdd(&out[(b * C_N + c) * 2 + 1], s2);
}

// ---------------- per-column (channel) sum/sumsq; perBatch: separate per batch ----------------
__global__ __launch_bounds__(256) void colstats_kernel(
    const float* __restrict__ Y, float* __restrict__ out, int perBatch) {
  int c = threadIdx.x;
  size_t r0 = (size_t)blockIdx.x * 64;
  float s1 = 0.f, s2 = 0.f;
  const float* base = Y + r0 * C_N + c;
  for (int r = 0; r < 64; r++) { float v = base[(size_t)r * C_N]; s1 += v; s2 += v * v; }
  int b = perBatch ? (int)(r0 / N_N) : 0;
  atomicAdd(&out[(b * C_N + c) * 2], s1);
  atomicAdd(&out[(b * C_N + c) * 2 + 1], s2);
}

// ---------------- h = relu(BN(IN(y1))) -> bf16 ; BN of IN is closed-form ----------------
__global__ __launch_bounds__(256) void h_kernel(
    const float* __restrict__ y1, const float* __restrict__ st,
    const float* __restrict__ bw, const float* __restrict__ bb, uint16_t* __restrict__ h) {
  size_t idx = ((size_t)blockIdx.x * 256 + threadIdx.x) * 4;
  int b = (int)(idx / NC);
  int c = (int)(idx % C_N);
  f32x4 y = *(const f32x4*)(y1 + idx);
  uint16_t ov[4];
#pragma unroll
  for (int j = 0; j < 4; j++) {
    int cc = c + j;
    float m0 = st[(0 * C_N + cc) * 2] * (1.f / N_N);
    float v0 = st[(0 * C_N + cc) * 2 + 1] * (1.f / N_N) - m0 * m0;
    float m1 = st[(1 * C_N + cc) * 2] * (1.f / N_N);
    float v1 = st[(1 * C_N + cc) * 2 + 1] * (1.f / N_N) - m1 * m1;
    float mb = b ? m1 : m0, vb = b ? v1 : v0;
    float vc = 0.5f * (v0 / (v0 + EPS_) + v1 / (v1 + EPS_)); // BN var of IN output
    float val = (y[j] - mb) * rsqrtf(vb + EPS_) * rsqrtf(vc + EPS_) * bw[cc] + bb[cc];
    ov[j] = f2bf(fmaxf(val, 0.f));
  }
  uint2 pk;
  pk.x = (uint32_t)ov[0] | ((uint32_t)ov[1] << 16);
  pk.y = (uint32_t)ov[2] | ((uint32_t)ov[3] << 16);
  *(uint2*)(h + idx) = pk;
}

// ---------------- final: out[b][c][n] = relu( BN2(IN2(y2)) + BN_r(y_r) ) ----------------
__global__ __launch_bounds__(256) void final_kernel(
    const float* __restrict__ y2, const float* __restrict__ yr,
    const float* __restrict__ st2, const float* __restrict__ strr,
    const float* __restrict__ g2, const float* __restrict__ be2,
    const float* __restrict__ gr, const float* __restrict__ ber, float* __restrict__ out) {
  __shared__ float t[32][33];
  int b = blockIdx.z;
  int n0 = blockIdx.x * 32, c0 = blockIdx.y * 32;
  int tc = threadIdx.x & 31, tr = threadIdx.x >> 5;
  int c = c0 + tc;
  float m20 = st2[(0 * C_N + c) * 2] * (1.f / N_N);
  float v20 = st2[(0 * C_N + c) * 2 + 1] * (1.f / N_N) - m20 * m20;
  float m21 = st2[(1 * C_N + c) * 2] * (1.f / N_N);
  float v21 = st2[(1 * C_N + c) * 2 + 1] * (1.f / N_N) - m21 * m21;
  float mb = b ? m21 : m20, vb = b ? v21 : v20;
  float inb = rsqrtf(vb + EPS_);
  float vc2 = 0.5f * (v20 / (v20 + EPS_) + v21 / (v21 + EPS_));
  float sc2 = rsqrtf(vc2 + EPS_) * g2[c];
  float mr = strr[c * 2] * (1.f / (B_N * N_N));
  float vr = strr[c * 2 + 1] * (1.f / (B_N * N_N)) - mr * mr;
  float scr = rsqrtf(vr + EPS_) * gr[c];
  const float* y2b = y2 + (size_t)b * NC;
  const float* yrb = yr + (size_t)b * NC;
#pragma unroll
  for (int pp = 0; pp < 4; pp++) {
    int r = tr + pp * 8;
    size_t off = (size_t)(n0 + r) * C_N + c;
    float a = (y2b[off] - mb) * inb * sc2 + be2[c];
    float x1 = (yrb[off] - mr) * scr + ber[c];
    t[r][tc] = fmaxf(a + x1, 0.f);
  }
  __syncthreads();
  float* ob = out + (size_t)b * C_N * N_N;
#pragma unroll
  for (int pp = 0; pp < 4; pp++) {
    int r = tr + pp * 8;
    ob[(size_t)(c0 + r) * N_N + n0 + tc] = t[tc][r];
  }
}

extern "C" void kernel_launch(void* const* d_in, const int* in_sizes, int n_in,
                              void* d_out, int out_size, void* d_ws, size_t ws_size,
                              hipStream_t stream) {
  (void)in_sizes; (void)n_in; (void)out_size;
  const float* x    = (const float*)d_in[0];
  const int*   em   = (const int*)  d_in[1];
  const float* ea   = (const float*)d_in[2];
  const float* lw   = (const float*)d_in[3];
  const float* wr   = (const float*)d_in[4];
  const float* br   = (const float*)d_in[5];
  const float* bnrw = (const float*)d_in[6];
  const float* bnrb = (const float*)d_in[7];
  const float* w1   = (const float*)d_in[8];
  const float* b1   = (const float*)d_in[9];
  const float* bn1w = (const float*)d_in[10];
  const float* bn1b = (const float*)d_in[11];
  const float* w2   = (const float*)d_in[12];
  const float* b2   = (const float*)d_in[13];
  const float* bn2w = (const float*)d_in[14];
  const float* bn2b = (const float*)d_in[15];

  char* p = (char*)d_ws;
  auto alloc = [&](size_t bytes) -> char* {
    char* r = p; p += (bytes + 255) & ~(size_t)255; return r;
  };
  // persistent small buffers
  uint16_t* xtb = (uint16_t*)alloc(2ULL * B_N * NC);   // x_t bf16 -> feat_attn bf16 (in place)
  uint16_t* qt  = (uint16_t*)alloc(2ULL * B_N * NC);   // q bf16 -> h bf16
  uint16_t* vcn = (uint16_t*)alloc(2ULL * B_N * NC);   // v bf16 (C,N)
  uint16_t* wb0 = (uint16_t*)alloc(2ULL * C_N * C_N);
  uint16_t* wb1 = (uint16_t*)alloc(2ULL * C_N * C_N);
  uint16_t* wb2 = (uint16_t*)alloc(2ULL * C_N * C_N);
  uint16_t* wb3 = (uint16_t*)alloc(2ULL * C_N * C_N);
  constexpr int STATS_F = 4 + 512 + 1024 + 1024;
  constexpr int RS_F = B_N * N_N;
  float* stats = (float*)alloc(sizeof(float) * (STATS_F + RS_F));
  float* vstats = stats;
  float* strr   = stats + 4;
  float* st1    = strr + 512;
  float* st2    = st1 + 1024;
  float* rowsum = stats + STATS_F;
  // big region (reused): feat / yr / y2 / y1
  float* feat = (float*)alloc(sizeof(float) * (size_t)B_N * NC);
  float* yr   = (float*)alloc(sizeof(float) * (size_t)B_N * NC);
  float* y2   = (float*)alloc(sizeof(float) * (size_t)B_N * NC);
  float* y1   = (float*)alloc(sizeof(float) * (size_t)B_N * NC);
  // split-m partials for fused attention
  size_t fixed = (size_t)(p - (char*)d_ws);
  size_t partsz = sizeof(float) * (size_t)B_N * NC;      // 8 MB per split
  int SPLITK = 4;
  while (SPLITK > 1 && fixed + (size_t)SPLITK * partsz > ws_size) SPLITK >>= 1;
  float* Opart = (float*)alloc((size_t)SPLITK * partsz);

  (void)hipMemsetAsync(stats, 0, sizeof(float) * (STATS_F + RS_F), stream);

  cast_w_kernel<<<dim3(C_N * C_N / 256, 4, 1), 256, 0, stream>>>(lw, wr, w1, w2, wb0, wb1, wb2, wb3);
  transpose_x_kernel<<<dim3(C_N / 32, N_N / 32, B_N), 256, 0, stream>>>(x, xtb);
  gemm_kernel<<<dim3(N_N / 64, C_N / 64, B_N), 256, 0, stream>>>(wb0, xtb, nullptr, feat);
  qv_kernel<<<dim3(N_N / 32, C_N / 32, B_N), 256, 0, stream>>>(feat, qt, vcn);
  attn_fused_kernel<<<dim3(N_N / 64, SPLITK, B_N), 256, 0, stream>>>(
      qt, vcn, ea, em, Opart, rowsum, N_N / SPLITK);
  combine_kernel<<<dim3((size_t)B_N * NC / 1024), 256, 0, stream>>>(Opart, rowsum, feat, vstats, SPLITK);
  fa_kernel<<<dim3((size_t)B_N * NC / 1024), 256, 0, stream>>>(feat, vstats, xtb);
  gemm_dual_kernel<<<dim3(N_N / 64, C_N / 64, B_N), 256, 0, stream>>>(wb1, wb2, xtb, br, b1, yr, y1);
  colstats_dual_kernel<<<dim3(B_N * N_N / 64, 2), 256, 0, stream>>>(yr, strr, y1, st1);
  h_kernel<<<dim3((size_t)B_N * NC / 1024), 256, 0, stream>>>(y1, st1, bn1w, bn1b, qt);
  gemm_kernel<<<dim3(N_N / 64, C_N / 64, B_N), 256, 0, stream>>>(wb3, qt, b2, y2);
  colstats_kernel<<<dim3(B_N * N_N / 64), 256, 0, stream>>>(y2, st2, 1);
  final_kernel<<<dim3(N_N / 32, C_N / 32, B_N), 256, 0, stream>>>(
      y2, yr, st2, strr, bn2w, bn2b, bnrw, bnrb, (float*)d_out);
}